// Round 2
// baseline (25.574 us; speedup 1.0000x reference)
//
#include <hip/hip_runtime.h>
#include <hip/hip_bf16.h>

// MF dot-product: out[i] = dot(table[x[i,0]], table[x[i,1] + N_USERS])
// x is int32 (JAX downcasts int64 without x64 enabled).
// 16 lanes per output row; each lane loads one float4 from each of the two
// 256B embedding rows (fully coalesced per row), then shfl_xor reduce.

#define N_USERS_OFFSET 1000000

__global__ __launch_bounds__(256) void mf_dot_kernel(
    const int* __restrict__ x,            // (batch, 2) int32
    const float* __restrict__ table,      // (2e6, 64) fp32
    float* __restrict__ out,              // (batch,) fp32
    int batch)
{
    int gid  = blockIdx.x * blockDim.x + threadIdx.x;
    int i    = gid >> 4;     // output row
    int lane = gid & 15;     // position within the 64-float row (float4 granules)
    if (i >= batch) return;

    // one int2 load gets both indices for the row
    int2 xi = reinterpret_cast<const int2*>(x)[i];
    long long u  = (long long)xi.x;
    long long it = (long long)xi.y + N_USERS_OFFSET;

    const float4* urow = reinterpret_cast<const float4*>(table + u  * 64) + lane;
    const float4* irow = reinterpret_cast<const float4*>(table + it * 64) + lane;

    float4 a = *urow;
    float4 b = *irow;

    float s = a.x * b.x + a.y * b.y + a.z * b.z + a.w * b.w;

    // reduce across the 16-lane group
    s += __shfl_xor(s, 1, 64);
    s += __shfl_xor(s, 2, 64);
    s += __shfl_xor(s, 4, 64);
    s += __shfl_xor(s, 8, 64);

    if (lane == 0) out[i] = s;
}

extern "C" void kernel_launch(void* const* d_in, const int* in_sizes, int n_in,
                              void* d_out, int out_size, void* d_ws, size_t ws_size,
                              hipStream_t stream) {
    const int* x         = (const int*)d_in[0];         // (BATCH, 2) int32
    const float* table   = (const float*)d_in[1];       // (2e6, 64) fp32
    float* out           = (float*)d_out;               // (BATCH,) fp32

    int batch = in_sizes[0] / 2;                        // 262144

    int threads = 256;
    long long total = (long long)batch * 16;
    int blocks = (int)((total + threads - 1) / threads);

    mf_dot_kernel<<<blocks, threads, 0, stream>>>(x, table, out, batch);
}